// Round 1
// baseline (98.491 us; speedup 1.0000x reference)
//
#include <hip/hip_runtime.h>
#include <math.h>

// Problem constants
#define B_  32
#define D_  64
#define L_  4096
#define E_  8
#define OC_ 32
#define LP_ 4094   // L - 2 (VALID conv, kernel 3)
#define TILE 256
#define NTILES 16  // ceil(4094/256)

// ---------------------------------------------------------------------------
// Prep kernel: blocks 0..31 compute gates + per-batch effective conv2 weights;
// block 32 transposes conv1_w from [oc][c][t] to [(c*3+t)][oc] for contiguous
// scalar (uniform) loads in the main kernel.
// ---------------------------------------------------------------------------
__global__ void prep_kernel(const float* __restrict__ x,
                            const float* __restrict__ w_gate,
                            const float* __restrict__ c1w,
                            const float* __restrict__ c2w,
                            const float* __restrict__ c2b,
                            float* __restrict__ weff,   // [B][32][32]
                            float* __restrict__ beff,   // [B][32]
                            float* __restrict__ wT)     // [192][32]
{
    const int b = blockIdx.x;
    if (b == B_) {
        // transpose conv1_w: c1w[oc*192 + (c*3+t)] -> wT[(c*3+t)*32 + oc]
        for (int i = threadIdx.x; i < OC_ * 192; i += blockDim.x) {
            int oc = i / 192, r = i % 192;
            wT[r * OC_ + oc] = c1w[i];
        }
        return;
    }

    const int d = threadIdx.x;  // 0..63, one channel per lane (single wave)
    // g_in[b, d*5+t] = x[b, d, 4090+t]
    float xv[5];
    #pragma unroll
    for (int t = 0; t < 5; ++t)
        xv[t] = x[((size_t)b * D_ + d) * L_ + (L_ - 6) + t];

    float part[E_];
    #pragma unroll
    for (int e = 0; e < E_; ++e) part[e] = 0.f;
    #pragma unroll
    for (int t = 0; t < 5; ++t) {
        const float* wg = w_gate + (d * 5 + t) * E_;
        #pragma unroll
        for (int e = 0; e < E_; ++e) part[e] += xv[t] * wg[e];
    }
    // full-wave butterfly reduce (64 lanes)
    #pragma unroll
    for (int off = 1; off < 64; off <<= 1) {
        #pragma unroll
        for (int e = 0; e < E_; ++e)
            part[e] += __shfl_xor(part[e], off, 64);
    }
    // softmax over 8 logits (every lane redundantly)
    float m = part[0];
    #pragma unroll
    for (int e = 1; e < E_; ++e) m = fmaxf(m, part[e]);
    float p[E_], s = 0.f;
    #pragma unroll
    for (int e = 0; e < E_; ++e) { p[e] = __expf(part[e] - m); s += p[e]; }
    // use precise expf for safety vs numpy reference
    s = 0.f;
    #pragma unroll
    for (int e = 0; e < E_; ++e) { p[e] = expf(part[e] - m); s += p[e]; }
    float inv = 1.f / s;
    #pragma unroll
    for (int e = 0; e < E_; ++e) p[e] *= inv;

    // top-2 (jax top_k: descending, lower index wins ties -> strict >)
    int i0 = 0;
    #pragma unroll
    for (int e = 1; e < E_; ++e) if (p[e] > p[i0]) i0 = e;
    int i1 = (i0 == 0) ? 1 : 0;
    #pragma unroll
    for (int e = 0; e < E_; ++e) {
        if (e == i0) continue;
        if (p[e] > p[i1]) i1 = e;
    }
    const float v0 = p[i0], v1 = p[i1];
    const float den = v0 + v1 + 1e-6f;
    const float g0 = v0 / den, g1 = v1 / den;

    // W_eff[b, dd, oc] = g0*c2w[(dd*8+i0)*32+oc] + g1*c2w[(dd*8+i1)*32+oc]
    for (int k = d; k < OC_ * OC_; k += 64) {
        int dd = k >> 5, oc = k & 31;
        weff[b * (OC_ * OC_) + k] =
            g0 * c2w[(dd * E_ + i0) * OC_ + oc] +
            g1 * c2w[(dd * E_ + i1) * OC_ + oc];
    }
    if (d < OC_)
        beff[b * OC_ + d] = g0 * c2b[d * E_ + i0] + g1 * c2b[d * E_ + i1];
}

// ---------------------------------------------------------------------------
// Main fused kernel: conv1 (K=3) + bias + tanh + per-batch 32x32 GEMV + store.
// One block = one (batch, 256-wide L tile). Thread t owns output position
// l = l0 + t, accumulating all 32 oc channels in registers.
// ---------------------------------------------------------------------------
__global__ __launch_bounds__(256, 2)
void fused_main(const float* __restrict__ x,
                const float* __restrict__ wT,    // [192][32]
                const float* __restrict__ weff,  // [B][32][32]
                const float* __restrict__ beff,  // [B][32]
                const float* __restrict__ c1b,   // [32]
                float* __restrict__ out)         // [B][32][4094]
{
    __shared__ float xs[D_][260];  // pitch 260 floats (16B-aligned rows)

    const int b    = blockIdx.x >> 4;
    const int l0   = (blockIdx.x & 15) * TILE;
    const int tid  = threadIdx.x;
    const float* xb = x + (size_t)b * D_ * L_;

    // Stage x tile: 64 rows x 256 floats via float4 (aligned: l0 % 256 == 0),
    // 4 rows per pass (256 threads = 4 x 64 lanes).
    {
        const int r  = tid >> 6;        // 0..3
        const int j4 = (tid & 63) * 4;  // 0..252
        #pragma unroll
        for (int cb = 0; cb < D_; cb += 4) {
            const int c = cb + r;
            float4 v = *(const float4*)(xb + (size_t)c * L_ + l0 + j4);
            *(float4*)(&xs[c][j4]) = v;
        }
        // tail columns 256, 257 (guard: last tile would read l=4096,4097)
        if (tid < 128) {
            const int c  = tid >> 1;
            const int jj = tid & 1;
            const int lg = l0 + TILE + jj;
            xs[c][TILE + jj] = (lg < L_) ? xb[(size_t)c * L_ + lg] : 0.f;
        }
    }
    __syncthreads();

    const int l = l0 + tid;
    if (l >= LP_) return;  // no barriers after this point

    float acc[OC_];
    #pragma unroll
    for (int oc = 0; oc < OC_; ++oc) acc[oc] = 0.f;

    for (int c = 0; c < D_; ++c) {
        const float x0 = xs[c][tid];
        const float x1 = xs[c][tid + 1];
        const float x2 = xs[c][tid + 2];
        const float* w = wT + c * (3 * OC_);  // uniform -> scalar loads
        #pragma unroll
        for (int oc = 0; oc < OC_; ++oc) acc[oc] += w[oc]        * x0;
        #pragma unroll
        for (int oc = 0; oc < OC_; ++oc) acc[oc] += w[OC_ + oc]  * x1;
        #pragma unroll
        for (int oc = 0; oc < OC_; ++oc) acc[oc] += w[2*OC_ + oc]* x2;
    }

    #pragma unroll
    for (int oc = 0; oc < OC_; ++oc)
        acc[oc] = tanhf(acc[oc] + c1b[oc]);

    const float* W  = weff + b * (OC_ * OC_);  // uniform per block
    const float* Bb = beff + b * OC_;
    float* ob = out + (size_t)b * OC_ * LP_ + l;

    #pragma unroll
    for (int dd = 0; dd < OC_; ++dd) {
        float s = Bb[dd];
        #pragma unroll
        for (int oc = 0; oc < OC_; ++oc) s += W[dd * OC_ + oc] * acc[oc];
        ob[(size_t)dd * LP_] = s;
    }
}

// ---------------------------------------------------------------------------
extern "C" void kernel_launch(void* const* d_in, const int* in_sizes, int n_in,
                              void* d_out, int out_size, void* d_ws, size_t ws_size,
                              hipStream_t stream)
{
    const float* x      = (const float*)d_in[0];
    const float* w_gate = (const float*)d_in[1];
    const float* c1w    = (const float*)d_in[2];
    const float* c1b    = (const float*)d_in[3];
    const float* c2w    = (const float*)d_in[4];
    const float* c2b    = (const float*)d_in[5];
    float* out = (float*)d_out;

    float* ws   = (float*)d_ws;
    float* weff = ws;                       // 32*1024 floats
    float* beff = ws + B_ * OC_ * OC_;      // 1024 floats
    float* wT   = beff + B_ * OC_;          // 6144 floats

    prep_kernel<<<B_ + 1, 64, 0, stream>>>(x, w_gate, c1w, c2w, c2b,
                                           weff, beff, wT);
    fused_main<<<B_ * NTILES, 256, 0, stream>>>(x, wT, weff, beff, c1b, out);
}

// Round 2
// 25.277 us; speedup vs baseline: 3.8965x; 3.8965x over previous
//
#include <hip/hip_runtime.h>
#include <math.h>

// Problem constants
#define B_  32
#define D_  64
#define L_  4096
#define E_  8
#define OC_ 32
#define LP_ 4094   // L - 2 (VALID conv, kernel 3)
#define TILE 256
#define NTILES 16  // 4096/256

typedef __attribute__((ext_vector_type(8)))  short short8;
typedef __attribute__((ext_vector_type(16))) float float16;

static __device__ __forceinline__ unsigned short f2bf(float f) {
    unsigned u = __float_as_uint(f);
    unsigned r = (u + 0x7fffu + ((u >> 16) & 1u)) >> 16;
    return (unsigned short)r;
}

// ---------------------------------------------------------------------------
// Workspace layout (bytes):
//   beff : f32 [32][32]           @ 0      (4096 B)
//   aF   : bf16 [12][64][8]       @ 4096   (12288 B)   conv1 A-fragments
//   wf2  : bf16 [B][2][64][8]     @ 16384  (65536 B)   per-batch Weff A-frags
// ---------------------------------------------------------------------------

// Prep: blocks 0..31 = gates + Weff fragments + beff; block 32 = conv1 A-frags.
__global__ void prep_kernel(const float* __restrict__ x,
                            const float* __restrict__ w_gate,
                            const float* __restrict__ c1w,
                            const float* __restrict__ c2w,
                            const float* __restrict__ c2b,
                            float* __restrict__ beff,            // [B][32]
                            unsigned short* __restrict__ aF,     // [12][64][8]
                            unsigned short* __restrict__ wf2)    // [B][2][64][8]
{
    const int b = blockIdx.x;
    const int lane = threadIdx.x;  // 64 threads

    if (b == B_) {
        // conv1 weight fragments: A[m=oc][k'], k' = t*64 + c  (t=k'/64, c=k'%64)
        // frag slot: lane holds k' = ks*16 + 8*(lane>>5) + i, oc = lane&31
        const int oc = lane & 31, half = lane >> 5;
        for (int ks = 0; ks < 12; ++ks) {
            #pragma unroll
            for (int i = 0; i < 8; ++i) {
                int kp = ks * 16 + half * 8 + i;
                int t = kp >> 6, c = kp & 63;
                aF[(ks * 64 + lane) * 8 + i] = f2bf(c1w[oc * 192 + c * 3 + t]);
            }
        }
        return;
    }

    const int d = lane;  // one channel per lane (single wave)
    float xv[5];
    #pragma unroll
    for (int t = 0; t < 5; ++t)
        xv[t] = x[((size_t)b * D_ + d) * L_ + (L_ - 6) + t];

    float part[E_];
    #pragma unroll
    for (int e = 0; e < E_; ++e) part[e] = 0.f;
    #pragma unroll
    for (int t = 0; t < 5; ++t) {
        const float* wg = w_gate + (d * 5 + t) * E_;
        #pragma unroll
        for (int e = 0; e < E_; ++e) part[e] += xv[t] * wg[e];
    }
    #pragma unroll
    for (int off = 1; off < 64; off <<= 1) {
        #pragma unroll
        for (int e = 0; e < E_; ++e)
            part[e] += __shfl_xor(part[e], off, 64);
    }
    float m = part[0];
    #pragma unroll
    for (int e = 1; e < E_; ++e) m = fmaxf(m, part[e]);
    float p[E_], s = 0.f;
    #pragma unroll
    for (int e = 0; e < E_; ++e) { p[e] = expf(part[e] - m); s += p[e]; }
    float inv = 1.f / s;
    #pragma unroll
    for (int e = 0; e < E_; ++e) p[e] *= inv;

    int i0 = 0;
    #pragma unroll
    for (int e = 1; e < E_; ++e) if (p[e] > p[i0]) i0 = e;
    int i1 = (i0 == 0) ? 1 : 0;
    #pragma unroll
    for (int e = 0; e < E_; ++e) {
        if (e == i0) continue;
        if (p[e] > p[i1]) i1 = e;
    }
    const float v0 = p[i0], v1 = p[i1];
    const float den = v0 + v1 + 1e-6f;
    const float g0 = v0 / den, g1 = v1 / den;

    // Weff A-fragments: A[m=dd][k=oc]; lane holds oc = ks*16 + 8*(lane>>5)+i
    {
        const int dd = lane & 31, half = lane >> 5;
        #pragma unroll
        for (int ks = 0; ks < 2; ++ks) {
            #pragma unroll
            for (int i = 0; i < 8; ++i) {
                int oc = ks * 16 + half * 8 + i;
                float v = g0 * c2w[(dd * E_ + i0) * OC_ + oc]
                        + g1 * c2w[(dd * E_ + i1) * OC_ + oc];
                wf2[((b * 2 + ks) * 64 + lane) * 8 + i] = f2bf(v);
            }
        }
    }
    if (d < OC_)
        beff[b * OC_ + d] = g0 * c2b[d * E_ + i0] + g1 * c2b[d * E_ + i1];
}

// ---------------------------------------------------------------------------
// Fused main: implicit-GEMM conv1 (MFMA) + tanh + Weff GEMM (MFMA) + store.
// Block = (batch, 256-col L-tile); 4 waves, each wave owns 2 col-tiles of 32.
// ---------------------------------------------------------------------------
__global__ __launch_bounds__(256, 3)
void fused_main(const float* __restrict__ x,
                const unsigned short* __restrict__ aF,   // [12][64][8]
                const unsigned short* __restrict__ wf2,  // [B][2][64][8]
                const float* __restrict__ beff,          // [B][32]
                const float* __restrict__ c1b,           // [32]
                float* __restrict__ out)                 // [B][32][4094]
{
    // xT: [260 rows(l)][64 c] bf16, row pitch 128 B, XOR-swizzled by (row&7)<<4
    __shared__ __align__(16) unsigned short xT[260 * 64];
    // H: per-wave [32 col][pitch 40] bf16
    __shared__ __align__(16) unsigned short Hl[4 * 32 * 40];

    const int tid  = threadIdx.x;
    const int lane = tid & 63;
    const int wv   = tid >> 6;
    const int b    = blockIdx.x >> 4;
    const int l0   = (blockIdx.x & 15) << 8;
    const float* xb = x + (size_t)b * (D_ * L_);

    // --- A fragments (same for all waves; L2-resident) ---
    short8 a1[12];
    #pragma unroll
    for (int ks = 0; ks < 12; ++ks)
        a1[ks] = *(const short8*)(aF + (ks * 64 + lane) * 8);
    short8 a2[2];
    #pragma unroll
    for (int ks = 0; ks < 2; ++ks)
        a2[ks] = *(const short8*)(wf2 + ((b * 2 + ks) * 64 + lane) * 8);

    const int hi = lane >> 5;
    float bias1[16], bias2[16];
    #pragma unroll
    for (int r = 0; r < 16; ++r) {
        int row = (r & 3) + 8 * (r >> 2) + 4 * hi;
        bias1[r] = c1b[row];
        bias2[r] = beff[b * 32 + row];
    }

    // --- stage x tile (transpose f32 [c][l] -> bf16 xT[l][c], c-pair packed) ---
    {
        const int c2 = tid >> 3;          // 0..31  (channel pair)
        const int jb = (tid & 7) << 2;    // 0,4,..,28
        const float* p0 = xb + (size_t)(2 * c2) * L_ + l0;
        const float* p1 = p0 + L_;
        #pragma unroll
        for (int jq = 0; jq < 8; ++jq) {
            int j = jq * 32 + jb;
            float4 v0 = *(const float4*)(p0 + j);
            float4 v1 = *(const float4*)(p1 + j);
            float e0[4] = {v0.x, v0.y, v0.z, v0.w};
            float e1[4] = {v1.x, v1.y, v1.z, v1.w};
            #pragma unroll
            for (int r = 0; r < 4; ++r) {
                int row = j + r;
                unsigned pk = (unsigned)f2bf(e0[r]) | ((unsigned)f2bf(e1[r]) << 16);
                int off = (row * 128 + c2 * 4) ^ ((row & 7) << 4);
                *(unsigned*)((char*)xT + off) = pk;
            }
        }
        // halo rows 256,257 (zero-fill past l=4095)
        if (tid < 64) {
            int cc2 = tid >> 1, jj = tid & 1;
            int row = 256 + jj;
            int lg = l0 + row;
            float f0 = 0.f, f1 = 0.f;
            if (lg < L_) {
                f0 = xb[(size_t)(2 * cc2) * L_ + lg];
                f1 = xb[(size_t)(2 * cc2 + 1) * L_ + lg];
            }
            unsigned pk = (unsigned)f2bf(f0) | ((unsigned)f2bf(f1) << 16);
            int off = (row * 128 + cc2 * 4) ^ ((row & 7) << 4);
            *(unsigned*)((char*)xT + off) = pk;
        }
    }
    __syncthreads();

    unsigned short* Hb = Hl + wv * (32 * 40);
    const int cl = lane & 31;
    float* outb = out + (size_t)b * (OC_ * (size_t)LP_);

    #pragma unroll
    for (int ct = 0; ct < 2; ++ct) {
        const int cb = wv * 64 + ct * 32;

        // conv1: 12 x mfma_32x32x16 over K' = t*64 + c
        float16 acc = (float16)0.0f;
        #pragma unroll
        for (int t = 0; t < 3; ++t) {
            int row = cb + cl + t;
            int rb = row * 128;
            int swz = (row & 7) << 4;
            #pragma unroll
            for (int q = 0; q < 4; ++q) {
                int off = (rb + q * 32 + hi * 16) ^ swz;
                short8 bf = *(const short8*)((const char*)xT + off);
                acc = __builtin_amdgcn_mfma_f32_32x32x16_bf16(a1[t * 4 + q], bf, acc, 0, 0, 0);
            }
        }

        // bias + tanh, write H (bf16) to wave-private LDS, row pairs packed
        #pragma unroll
        for (int j = 0; j < 8; ++j) {
            int r2 = 2 * j;
            int row = (r2 & 3) + 8 * (r2 >> 2) + 4 * hi;
            float h0 = tanhf(acc[r2]     + bias1[r2]);
            float h1 = tanhf(acc[r2 + 1] + bias1[r2 + 1]);
            unsigned pk = (unsigned)f2bf(h0) | ((unsigned)f2bf(h1) << 16);
            *(unsigned*)&Hb[cl * 40 + row] = pk;
        }

        // conv2: 2 x mfma, B = H[oc][col] from LDS
        float16 acc2 = (float16)0.0f;
        #pragma unroll
        for (int ks = 0; ks < 2; ++ks) {
            short8 bf = *(const short8*)&Hb[cl * 40 + ks * 16 + hi * 8];
            acc2 = __builtin_amdgcn_mfma_f32_32x32x16_bf16(a2[ks], bf, acc2, 0, 0, 0);
        }

        // store: D[row=dd][col] -> out[b][dd][l]
        int l = l0 + cb + cl;
        if (l < LP_) {
            #pragma unroll
            for (int r = 0; r < 16; ++r) {
                int row = (r & 3) + 8 * (r >> 2) + 4 * hi;
                outb[(size_t)row * LP_ + l] = acc2[r] + bias2[r];
            }
        }
    }
}

// ---------------------------------------------------------------------------
extern "C" void kernel_launch(void* const* d_in, const int* in_sizes, int n_in,
                              void* d_out, int out_size, void* d_ws, size_t ws_size,
                              hipStream_t stream)
{
    const float* x      = (const float*)d_in[0];
    const float* w_gate = (const float*)d_in[1];
    const float* c1w    = (const float*)d_in[2];
    const float* c1b    = (const float*)d_in[3];
    const float* c2w    = (const float*)d_in[4];
    const float* c2b    = (const float*)d_in[5];
    float* out = (float*)d_out;

    char* ws = (char*)d_ws;
    float* beff          = (float*)ws;                      // 4096 B
    unsigned short* aF   = (unsigned short*)(ws + 4096);    // 12288 B
    unsigned short* wf2  = (unsigned short*)(ws + 16384);   // 65536 B

    prep_kernel<<<B_ + 1, 64, 0, stream>>>(x, w_gate, c1w, c2w, c2b,
                                           beff, aF, wf2);
    fused_main<<<B_ * NTILES, 256, 0, stream>>>(x, aF, wf2, beff, c1b, out);
}